// Round 2
// baseline (173.401 us; speedup 1.0000x reference)
//
#include <hip/hip_runtime.h>

typedef __bf16 bf16x8 __attribute__((ext_vector_type(8)));
typedef float f32x4 __attribute__((ext_vector_type(4)));
typedef float f32x16 __attribute__((ext_vector_type(16)));
typedef unsigned int uint32;
typedef unsigned short u16;

#define NST 21
#define TOK 1003
#define SCL 0.3606737602222409f  // 0.25*log2(e); softmax = exp2(s), shift-free

union U4B { uint4 u; bf16x8 b; };

__device__ __forceinline__ uint32 pkbf(float a, float b) {  // RTNE pack
  uint32 ua = __float_as_uint(a), ub = __float_as_uint(b);
  ua += 0x7fffu + ((ua >> 16) & 1u);
  ub += 0x7fffu + ((ub >> 16) & 1u);
  return (ua >> 16) | (ub & 0xffff0000u);
}
__device__ __forceinline__ u16 bf1(float a) {
  uint32 u = __float_as_uint(a);
  u += 0x7fffu + ((u >> 16) & 1u);
  return (u16)(u >> 16);
}
// 1-instr truncating pack: lo16 = lo.hi16, hi16 = hi.hi16 (CK idiom)
__device__ __forceinline__ uint32 pkperm(float lo, float hi) {
  return __builtin_amdgcn_perm(__float_as_uint(hi), __float_as_uint(lo), 0x07060302u);
}

// =====================================================================
// prep: (a) 5 weight transposes -> bf16 WtAll (40 blocks, 8 per matrix),
// (b) station projections Q_st->Qm rows<21, K_s/V_s (+zero pad rows
// 21..32). q/hx cast fused into proj_pair. grid 552 = 40 + 512
// =====================================================================
__global__ __launch_bounds__(256) void prep(
    const float* __restrict__ q, const float* __restrict__ hx,
    const float* __restrict__ W0, const float* __restrict__ W1,
    const float* __restrict__ W2, const float* __restrict__ W3,
    const float* __restrict__ W4, const float* __restrict__ Wqst,
    const float* __restrict__ Wks, const float* __restrict__ Wvs,
    u16* __restrict__ WtAll, u16* __restrict__ Qm,
    u16* __restrict__ Ks, u16* __restrict__ Vs) {
  int bid = blockIdx.x, tid = threadIdx.x;
  __shared__ float xq2[2][128], xh2[2][128];
  if (bid < 40) {
    int w = bid >> 3, seg = bid & 7;
    const float* W = (w == 0) ? W0 : (w == 1) ? W1 : (w == 2) ? W2
                     : (w == 3) ? W3 : W4;
    u16* dst = WtAll + w * 16384;
#pragma unroll
    for (int it = 0; it < 8; ++it) {
      int i = seg * 2048 + it * 256 + tid;  // 0..16383
      int inner = i & 127, outer = i >> 7;
      float v;
      if (w < 4) {
        int h = outer >> 4, k = outer & 15;
        v = W[h * 2048 + inner * 16 + k];
      } else {
        v = W[inner * 128 + outer];
      }
      dst[outer * 128 + inner] = bf1(v);
    }
  } else {
    int t2 = bid - 40;              // 0..511
    int sub = tid >> 7, col = tid & 127;
    int hh = col >> 4, k = col & 15;
    int bs2 = t2 * 2 + sub;         // 0..1023
    int b2 = bs2 >> 5, s = bs2 & 31;
    if (s < NST) {
      xq2[sub][col] = q[(size_t)(b2 * 1024 + s) * 128 + col];
      xh2[sub][col] = hx[(size_t)(b2 * 1024 + s) * 128 + col];
    }
    __syncthreads();
    if (s < NST) {
      const float* Wq = Wqst + hh * 2048 + k;
      const float* Wk = Wks + hh * 2048 + k;
      const float* Wv = Wvs + hh * 2048 + k;
      float dq = 0.f, dk_ = 0.f, dv = 0.f;
#pragma unroll 8
      for (int d = 0; d < 128; ++d) {
        float xq = xq2[sub][d], xh = xh2[sub][d];
        dq = fmaf(xq, Wq[d * 16], dq);
        dk_ = fmaf(xh, Wk[d * 16], dk_);
        dv = fmaf(xh, Wv[d * 16], dv);
      }
      Qm[(((size_t)hh * 32 + b2) * 1024 + s) * 16 + k] = bf1(dq * SCL);
      Ks[(((size_t)hh * 32 + b2) * 32 + s) * 16 + k] = bf1(dk_);
      Vs[(((size_t)hh * 32 + b2) * 16 + k) * 32 + s] = bf1(dv);
    } else {
      Ks[(((size_t)hh * 32 + b2) * 32 + s) * 16 + k] = 0;
      Vs[(((size_t)hh * 32 + b2) * 16 + k) * 32 + s] = 0;
    }
  }
}

// =====================================================================
// proj_pair: one block computes BOTH projections sharing an A tile.
// pg=0: q -> Qm (mode0: scaled, skip n<21) and Qts (mode1: scaled)
// pg=1: hx -> Kc (mode2) and Vc (mode3: transposed [h][b][k16][n1024])
// A f32 read ONCE per tile, cast inline (RTNE pkbf, bit-identical to the
// old standalone cast). W staged twice per block (L2-resident).
// grid 1024 = 2 x 512
// =====================================================================
__global__ __launch_bounds__(256) void proj_pair(
    const float* __restrict__ q, const float* __restrict__ hx,
    const u16* __restrict__ WtAll, u16* __restrict__ Qm,
    u16* __restrict__ Qts, u16* __restrict__ Kc, u16* __restrict__ Vc) {
  __shared__ u16 Wl[128 * 136];
  int pg = blockIdx.x >> 9, mb = blockIdx.x & 511;
  int m0 = mb * 64;
  const float* A = pg ? hx : q;
  int tid = threadIdx.x;
  int wave = tid >> 6, lane = tid & 63;
  int quad = lane >> 4, l15 = lane & 15;
  int mrow = m0 + wave * 16 + l15;

  U4B af[4];
#pragma unroll
  for (int dk = 0; dk < 4; ++dk) {
    const float* Af = A + (size_t)mrow * 128 + dk * 32 + quad * 8;
    float4 a = *(const float4*)Af;
    float4 b = *(const float4*)(Af + 4);
    af[dk].u = make_uint4(pkbf(a.x, a.y), pkbf(a.z, a.w),
                          pkbf(b.x, b.y), pkbf(b.z, b.w));
  }

  int gbase = m0 + wave * 16 + quad * 4;
  int bb = gbase >> 10, n0 = gbase & 1023;

#pragma unroll
  for (int s = 0; s < 2; ++s) {
    int mode = pg * 2 + s;
    const u16* WtG = WtAll + mode * 16384;
    if (s) __syncthreads();  // all Wl reads of s=0 done before restage
#pragma unroll
    for (int r = 0; r < 8; ++r) {
      int i = r * 256 + tid;
      int e = i >> 4, j = i & 15;
      *(uint4*)&Wl[e * 136 + j * 8] = *(const uint4*)(WtG + e * 128 + j * 8);
    }
    __syncthreads();

    f32x4 c[8];
#pragma unroll
    for (int nt = 0; nt < 8; ++nt)
#pragma unroll
      for (int r = 0; r < 4; ++r) c[nt][r] = 0.f;
#pragma unroll
    for (int dk = 0; dk < 4; ++dk)
#pragma unroll
      for (int nt = 0; nt < 8; ++nt) {
        U4B bg;
        bg.u = *(const uint4*)&Wl[(nt * 16 + l15) * 136 + dk * 32 + quad * 8];
        c[nt] = __builtin_amdgcn_mfma_f32_16x16x32_bf16(af[dk].b, bg.b, c[nt], 0, 0, 0);
      }

    if (mode == 0) {
#pragma unroll
      for (int nt = 0; nt < 8; ++nt)
#pragma unroll
        for (int r = 0; r < 4; ++r) {
          int n = n0 + r;
          if (n < NST) continue;  // prep owns station rows of Qm
          Qm[(((size_t)nt * 32 + bb) * 1024 + n) * 16 + l15] = bf1(c[nt][r] * SCL);
        }
    } else if (mode == 1) {
#pragma unroll
      for (int nt = 0; nt < 8; ++nt)
#pragma unroll
        for (int r = 0; r < 4; ++r)
          Qts[(((size_t)nt * 32 + bb) * 1024 + n0 + r) * 16 + l15] =
              bf1(c[nt][r] * SCL);
    } else if (mode == 2) {
#pragma unroll
      for (int nt = 0; nt < 8; ++nt)
#pragma unroll
        for (int r = 0; r < 4; ++r)
          Kc[(((size_t)nt * 32 + bb) * 1024 + n0 + r) * 16 + l15] = bf1(c[nt][r]);
    } else {
#pragma unroll
      for (int nt = 0; nt < 8; ++nt) {
        uint2 w2 = make_uint2(pkbf(c[nt][0], c[nt][1]), pkbf(c[nt][2], c[nt][3]));
        *(uint2*)(Vc + (((size_t)nt * 32 + bb) * 16 + l15) * 1024 + n0) = w2;
      }
    }
  }
}

// =====================================================================
// outproj: out(64 x 128) f32 = heads_bf16(64x128) @ W_out^T
// =====================================================================
__global__ __launch_bounds__(256) void outproj(
    const u16* __restrict__ heads, const u16* __restrict__ WtAll,
    float* __restrict__ out) {
  __shared__ u16 Wl[128 * 136];
  const u16* WtG = WtAll + 4 * 16384;
  int tid = threadIdx.x;
#pragma unroll
  for (int r = 0; r < 8; ++r) {
    int i = r * 256 + tid;
    int e = i >> 4, j = i & 15;
    *(uint4*)&Wl[e * 136 + j * 8] = *(const uint4*)(WtG + e * 128 + j * 8);
  }
  __syncthreads();
  int wave = tid >> 6, lane = tid & 63;
  int quad = lane >> 4, l15 = lane & 15;
  int m0 = blockIdx.x * 64;
  int mrow = m0 + wave * 16 + l15;

  f32x4 c[8];
#pragma unroll
  for (int nt = 0; nt < 8; ++nt)
#pragma unroll
    for (int r = 0; r < 4; ++r) c[nt][r] = 0.f;
#pragma unroll
  for (int dk = 0; dk < 4; ++dk) {
    U4B af;
    af.u = *(const uint4*)(heads + (size_t)mrow * 128 + dk * 32 + quad * 8);
#pragma unroll
    for (int nt = 0; nt < 8; ++nt) {
      U4B bg;
      bg.u = *(const uint4*)&Wl[(nt * 16 + l15) * 136 + dk * 32 + quad * 8];
      c[nt] = __builtin_amdgcn_mfma_f32_16x16x32_bf16(af.b, bg.b, c[nt], 0, 0, 0);
    }
  }
  int gbase = m0 + wave * 16 + quad * 4;
#pragma unroll
  for (int nt = 0; nt < 8; ++nt)
#pragma unroll
    for (int r = 0; r < 4; ++r)
      out[(size_t)(gbase + r) * 128 + nt * 16 + l15] = c[nt][r];
}

// =====================================================================
// attn_main (r5 skeleton + T14 register prefetch of next K/V tile):
// per (h,b,qc): 256 q rows over 1024 key slots (keys<21 masked at kb0/kt0),
// then one masked station kt-step (keys>=21 masked) from KsL/VsL.
// S^T via mfma_32x32x16; exp2 shift-free; P packed with v_perm;
// PV + row-sum via mfma_16x16x32 (ones-B). Straight-line, unroll 1.
// Prefetch: tile kb+1's global loads issue right after tile kb's ds_write,
// completing under the 4-kt compute phase (~>1000 cyc) -> staging latency
// off the critical path. Barrier count per iter unchanged (2).
// =====================================================================
__global__ __launch_bounds__(256) void attn_main(
    const u16* __restrict__ Qm, const u16* __restrict__ Qts,
    const u16* __restrict__ Kc, const u16* __restrict__ Vc,
    const u16* __restrict__ Ks, const u16* __restrict__ Vs,
    u16* __restrict__ heads) {
  int bx = blockIdx.x;
  int hb = bx & 255, qc = bx >> 8;
  int h = hb >> 5, b = hb & 31;
  int tid = threadIdx.x;
  int wave = tid >> 6, lane = tid & 63;
  int l5 = lane >> 5, l31 = lane & 31;
  int quad = lane >> 4, l15 = lane & 15;

  __shared__ u16 Kl[128 * 26];     // [key][26]: 52B rows, 13-bank step (gcd 1)
  __shared__ u16 Vl[16 * 140];     // [k][140]: 280B rows (gcd 2)
  __shared__ u16 Pt[4][64 * 36];   // per wave [q][36]: 72B rows (gcd 2)
  __shared__ u16 KsL[32 * 26];     // station keys
  __shared__ u16 VsL[16 * 44];     // station values transposed

  const u16* Qbase = Qm + ((size_t)(h * 32 + b)) * 16384;
  const u16* QtsB = Qts + ((size_t)(h * 32 + b)) * 16384;
  const u16* Kbase = Kc + ((size_t)(h * 32 + b)) * 16384;
  const u16* Vbase = Vc + ((size_t)(h * 32 + b)) * 16384;
  const u16* KsB = Ks + (size_t)(h * 32 + b) * 512;
  const u16* VsB = Vs + (size_t)(h * 32 + b) * 512;

  // stage station K/V once (visible after first loop barrier)
  if (tid < 64) {
    int key = tid >> 1, half = tid & 1;
    *(uint4*)&KsL[key * 26 + half * 8] = *(const uint4*)(KsB + key * 16 + half * 8);
  } else if (tid < 128) {
    int t = tid - 64;
    int d = t >> 2, kg = t & 3;
    *(uint4*)&VsL[d * 44 + kg * 8] = *(const uint4*)(VsB + d * 32 + kg * 8);
  }

  int qw0 = qc * 256 + wave * 64;
  U4B qf0, qf1;
  qf0.u = *(const uint4*)(Qbase + (size_t)(qw0 + l31) * 16 + l5 * 8);
  qf1.u = *(const uint4*)(Qbase + (size_t)(qw0 + 32 + l31) * 16 + l5 * 8);

  // T14 prefetch: tile 0 into regs
  int skey = tid >> 1, shalf = tid & 1;   // K stage mapping
  int sd = tid >> 4, skg = tid & 15;      // V stage mapping
  uint4 kpre = *(const uint4*)(Kbase + (size_t)skey * 16 + shalf * 8);
  uint4 vpre = *(const uint4*)(Vbase + (size_t)sd * 1024 + skg * 8);

  f32x16 zero16;
#pragma unroll
  for (int i = 0; i < 16; ++i) zero16[i] = 0.f;
  U4B ones;
  ones.u = make_uint4(0x3F803F80u, 0x3F803F80u, 0x3F803F80u, 0x3F803F80u);

  f32x4 o[4], la[4];
#pragma unroll
  for (int mt = 0; mt < 4; ++mt)
#pragma unroll
    for (int r = 0; r < 4; ++r) { o[mt][r] = 0.f; la[mt][r] = 0.f; }

#pragma unroll 1
  for (int kb = 0; kb < 8; ++kb) {
    __syncthreads();  // previous tile's compute done reading Kl/Vl
    *(uint4*)&Kl[skey * 26 + shalf * 8] = kpre;
    *(uint4*)&Vl[sd * 140 + skg * 8] = vpre;
    if (kb < 7) {  // issue next tile; completes under this tile's compute
      int j0n = (kb + 1) * 128;
      kpre = *(const uint4*)(Kbase + (size_t)(j0n + skey) * 16 + shalf * 8);
      vpre = *(const uint4*)(Vbase + (size_t)sd * 1024 + j0n + skg * 8);
    }
    __syncthreads();
#pragma unroll 1
    for (int kt = 0; kt < 4; ++kt) {
      int key0 = kt * 32;
      U4B af;
      af.u = *(const uint4*)&Kl[(key0 + l31) * 26 + l5 * 8];
      f32x16 c0 =
          __builtin_amdgcn_mfma_f32_32x32x16_bf16(af.b, qf0.b, zero16, 0, 0, 0);
      f32x16 c1 =
          __builtin_amdgcn_mfma_f32_32x32x16_bf16(af.b, qf1.b, zero16, 0, 0, 0);
      bool masked = (kb == 0) && (kt == 0);
#pragma unroll
      for (int f = 0; f < 2; ++f) {
        const f32x16& c = f ? c1 : c0;
        int qq = f * 32 + l31;
#pragma unroll
        for (int g = 0; g < 4; ++g) {
          float p0 = __builtin_amdgcn_exp2f(c[4 * g + 0]);
          float p1 = __builtin_amdgcn_exp2f(c[4 * g + 1]);
          float p2 = __builtin_amdgcn_exp2f(c[4 * g + 2]);
          float p3 = __builtin_amdgcn_exp2f(c[4 * g + 3]);
          if (masked) {  // key index of value r is r + 8*g + 4*l5; zero keys<21
            int kb0 = 8 * g + 4 * l5;
            p0 = (kb0 + 0 < NST) ? 0.f : p0;
            p1 = (kb0 + 1 < NST) ? 0.f : p1;
            p2 = (kb0 + 2 < NST) ? 0.f : p2;
            p3 = (kb0 + 3 < NST) ? 0.f : p3;
          }
          uint2 w2 = make_uint2(pkperm(p0, p1), pkperm(p2, p3));
          *(uint2*)&Pt[wave][qq * 36 + 4 * l5 + 8 * g] = w2;
        }
      }
      U4B vf;
      vf.u = *(const uint4*)&Vl[l15 * 140 + key0 + quad * 8];
#pragma unroll
      for (int mt = 0; mt < 4; ++mt) {
        U4B pf;
        pf.u = *(const uint4*)&Pt[wave][(mt * 16 + l15) * 36 + quad * 8];
        o[mt] = __builtin_amdgcn_mfma_f32_16x16x32_bf16(pf.b, vf.b, o[mt], 0, 0, 0);
        la[mt] =
            __builtin_amdgcn_mfma_f32_16x16x32_bf16(pf.b, ones.b, la[mt], 0, 0, 0);
      }
    }
  }

  // ---- fused station pass: Q = Q_ts, keys = K_s/V_s (keys>=21 masked) ----
  f32x4 o2[4], la2[4];
#pragma unroll
  for (int mt = 0; mt < 4; ++mt)
#pragma unroll
    for (int r = 0; r < 4; ++r) { o2[mt][r] = 0.f; la2[mt][r] = 0.f; }
  qf0.u = *(const uint4*)(QtsB + (size_t)(qw0 + l31) * 16 + l5 * 8);
  qf1.u = *(const uint4*)(QtsB + (size_t)(qw0 + 32 + l31) * 16 + l5 * 8);
  {
    U4B af;
    af.u = *(const uint4*)&KsL[l31 * 26 + l5 * 8];
    f32x16 c0 =
        __builtin_amdgcn_mfma_f32_32x32x16_bf16(af.b, qf0.b, zero16, 0, 0, 0);
    f32x16 c1 =
        __builtin_amdgcn_mfma_f32_32x32x16_bf16(af.b, qf1.b, zero16, 0, 0, 0);
#pragma unroll
    for (int f = 0; f < 2; ++f) {
      const f32x16& c = f ? c1 : c0;
      int qq = f * 32 + l31;
#pragma unroll
      for (int g = 0; g < 4; ++g) {
        float p0 = __builtin_amdgcn_exp2f(c[4 * g + 0]);
        float p1 = __builtin_amdgcn_exp2f(c[4 * g + 1]);
        float p2 = __builtin_amdgcn_exp2f(c[4 * g + 2]);
        float p3 = __builtin_amdgcn_exp2f(c[4 * g + 3]);
        int kb0 = 8 * g + 4 * l5;  // zero keys >= 21 (pad rows)
        p0 = (kb0 + 0 >= NST) ? 0.f : p0;
        p1 = (kb0 + 1 >= NST) ? 0.f : p1;
        p2 = (kb0 + 2 >= NST) ? 0.f : p2;
        p3 = (kb0 + 3 >= NST) ? 0.f : p3;
        uint2 w2 = make_uint2(pkperm(p0, p1), pkperm(p2, p3));
        *(uint2*)&Pt[wave][qq * 36 + 4 * l5 + 8 * g] = w2;
      }
    }
    U4B vf;
    vf.u = *(const uint4*)&VsL[l15 * 44 + quad * 8];
#pragma unroll
    for (int mt = 0; mt < 4; ++mt) {
      U4B pf;
      pf.u = *(const uint4*)&Pt[wave][(mt * 16 + l15) * 36 + quad * 8];
      o2[mt] = __builtin_amdgcn_mfma_f32_16x16x32_bf16(pf.b, vf.b, o2[mt], 0, 0, 0);
      la2[mt] =
          __builtin_amdgcn_mfma_f32_16x16x32_bf16(pf.b, ones.b, la2[mt], 0, 0, 0);
    }
  }

  // ---- epilogue: heads bf16 ----
#pragma unroll
  for (int mt = 0; mt < 4; ++mt)
#pragma unroll
    for (int r = 0; r < 4; ++r) {
      int n = qw0 + mt * 16 + quad * 4 + r;
      float val = o[mt][r] * __builtin_amdgcn_rcpf(la[mt][r]);
      if (n >= NST) val += o2[mt][r] * __builtin_amdgcn_rcpf(la2[mt][r]);
      heads[((size_t)b * 1024 + n) * 128 + h * 16 + l15] = bf1(val);
    }
}

// =====================================================================
extern "C" void kernel_launch(void* const* d_in, const int* in_sizes, int n_in,
                              void* d_out, int out_size, void* d_ws,
                              size_t ws_size, hipStream_t stream) {
  (void)in_sizes; (void)n_in; (void)out_size; (void)ws_size;
  const float* q     = (const float*)d_in[0];
  const float* hx    = (const float*)d_in[1];
  const float* W_qts = (const float*)d_in[2];  // W_query_custom   -> Q_ts
  const float* W_qtt = (const float*)d_in[3];  // W_query_custom_1 -> Q_tt
  const float* W_kc  = (const float*)d_in[4];
  const float* W_vc  = (const float*)d_in[5];
  const float* W_qst = (const float*)d_in[6];  // W_query_charge_1 -> Q_st
  const float* W_ks  = (const float*)d_in[7];
  const float* W_vs  = (const float*)d_in[8];
  const float* W_out = (const float*)d_in[9];

  char* ws = (char*)d_ws;
  u16* heads = (u16*)(ws + 0);          // bf16 heads
  u16* Qm    = (u16*)(ws + 16777216);   // [h][b][1024][16]
  u16* Qts   = (u16*)(ws + 25165824);
  u16* Kc    = (u16*)(ws + 33554432);   // [h][b][1024][16]
  u16* Vc    = (u16*)(ws + 41943040);   // [h][b][16][1024] (transposed)
  u16* Ks    = (u16*)(ws + 50331648);   // [h][b][32][16]
  u16* Vs    = (u16*)(ws + 50593792);   // [h][b][16][32]
  u16* WtAll = (u16*)(ws + 50855936);   // 5 x 128x128 bf16

  hipLaunchKernelGGL(prep, dim3(552), dim3(256), 0, stream,
                     q, hx, W_qtt, W_qts, W_kc, W_vc, W_out, W_qst, W_ks, W_vs,
                     WtAll, Qm, Ks, Vs);
  hipLaunchKernelGGL(proj_pair, dim3(1024), dim3(256), 0, stream,
                     q, hx, WtAll, Qm, Qts, Kc, Vc);
  hipLaunchKernelGGL(attn_main, dim3(1024), dim3(256), 0, stream,
                     Qm, Qts, Kc, Vc, Ks, Vs, heads);
  hipLaunchKernelGGL(outproj, dim3(512), dim3(256), 0, stream,
                     heads, WtAll, (float*)d_out);
}

// Round 3
// 169.507 us; speedup vs baseline: 1.0230x; 1.0230x over previous
//
#include <hip/hip_runtime.h>

typedef __bf16 bf16x8 __attribute__((ext_vector_type(8)));
typedef float f32x4 __attribute__((ext_vector_type(4)));
typedef float f32x16 __attribute__((ext_vector_type(16)));
typedef unsigned int uint32;
typedef unsigned short u16;

#define NST 21
#define TOK 1003
#define SCL 0.3606737602222409f  // 0.25*log2(e); softmax = exp2(s), shift-free

union U4B { uint4 u; bf16x8 b; };

__device__ __forceinline__ uint32 pkbf(float a, float b) {  // RTNE pack
  uint32 ua = __float_as_uint(a), ub = __float_as_uint(b);
  ua += 0x7fffu + ((ua >> 16) & 1u);
  ub += 0x7fffu + ((ub >> 16) & 1u);
  return (ua >> 16) | (ub & 0xffff0000u);
}
__device__ __forceinline__ u16 bf1(float a) {
  uint32 u = __float_as_uint(a);
  u += 0x7fffu + ((u >> 16) & 1u);
  return (u16)(u >> 16);
}
// 1-instr truncating pack: lo16 = lo.hi16, hi16 = hi.hi16 (CK idiom)
__device__ __forceinline__ uint32 pkperm(float lo, float hi) {
  return __builtin_amdgcn_perm(__float_as_uint(hi), __float_as_uint(lo), 0x07060302u);
}

// =====================================================================
// prep: (a) 5 weight transposes -> bf16 WtAll (40 blocks, 8 per matrix),
// (b) station projections Q_st->Qm rows<21, K_s/V_s (+zero pad rows
// 21..32). grid 552 = 40 + 512
// =====================================================================
__global__ __launch_bounds__(256) void prep(
    const float* __restrict__ q, const float* __restrict__ hx,
    const float* __restrict__ W0, const float* __restrict__ W1,
    const float* __restrict__ W2, const float* __restrict__ W3,
    const float* __restrict__ W4, const float* __restrict__ Wqst,
    const float* __restrict__ Wks, const float* __restrict__ Wvs,
    u16* __restrict__ WtAll, u16* __restrict__ Qm,
    u16* __restrict__ Ks, u16* __restrict__ Vs) {
  int bid = blockIdx.x, tid = threadIdx.x;
  __shared__ float xq2[2][128], xh2[2][128];
  if (bid < 40) {
    int w = bid >> 3, seg = bid & 7;
    const float* W = (w == 0) ? W0 : (w == 1) ? W1 : (w == 2) ? W2
                     : (w == 3) ? W3 : W4;
    u16* dst = WtAll + w * 16384;
#pragma unroll
    for (int it = 0; it < 8; ++it) {
      int i = seg * 2048 + it * 256 + tid;  // 0..16383
      int inner = i & 127, outer = i >> 7;
      float v;
      if (w < 4) {
        int h = outer >> 4, k = outer & 15;
        v = W[h * 2048 + inner * 16 + k];
      } else {
        v = W[inner * 128 + outer];
      }
      dst[outer * 128 + inner] = bf1(v);
    }
  } else {
    int t2 = bid - 40;              // 0..511
    int sub = tid >> 7, col = tid & 127;
    int hh = col >> 4, k = col & 15;
    int bs2 = t2 * 2 + sub;         // 0..1023
    int b2 = bs2 >> 5, s = bs2 & 31;
    if (s < NST) {
      xq2[sub][col] = q[(size_t)(b2 * 1024 + s) * 128 + col];
      xh2[sub][col] = hx[(size_t)(b2 * 1024 + s) * 128 + col];
    }
    __syncthreads();
    if (s < NST) {
      const float* Wq = Wqst + hh * 2048 + k;
      const float* Wk = Wks + hh * 2048 + k;
      const float* Wv = Wvs + hh * 2048 + k;
      float dq = 0.f, dk_ = 0.f, dv = 0.f;
#pragma unroll 8
      for (int d = 0; d < 128; ++d) {
        float xq = xq2[sub][d], xh = xh2[sub][d];
        dq = fmaf(xq, Wq[d * 16], dq);
        dk_ = fmaf(xh, Wk[d * 16], dk_);
        dv = fmaf(xh, Wv[d * 16], dv);
      }
      Qm[(((size_t)hh * 32 + b2) * 1024 + s) * 16 + k] = bf1(dq * SCL);
      Ks[(((size_t)hh * 32 + b2) * 32 + s) * 16 + k] = bf1(dk_);
      Vs[(((size_t)hh * 32 + b2) * 16 + k) * 32 + s] = bf1(dv);
    } else {
      Ks[(((size_t)hh * 32 + b2) * 32 + s) * 16 + k] = 0;
      Vs[(((size_t)hh * 32 + b2) * 16 + k) * 32 + s] = 0;
    }
  }
}

// =====================================================================
// proj_pair: one block computes BOTH projections sharing an A tile.
// pg=0: q -> Qm (mode0: scaled, skip n<21) and Qts (mode1: scaled)
// pg=1: hx -> Kc (mode2) and Vc (mode3: transposed [h][b][k16][n1024])
// grid 1024 = 2 x 512
// =====================================================================
__global__ __launch_bounds__(256) void proj_pair(
    const float* __restrict__ q, const float* __restrict__ hx,
    const u16* __restrict__ WtAll, u16* __restrict__ Qm,
    u16* __restrict__ Qts, u16* __restrict__ Kc, u16* __restrict__ Vc) {
  __shared__ u16 Wl[128 * 136];
  int pg = blockIdx.x >> 9, mb = blockIdx.x & 511;
  int m0 = mb * 64;
  const float* A = pg ? hx : q;
  int tid = threadIdx.x;
  int wave = tid >> 6, lane = tid & 63;
  int quad = lane >> 4, l15 = lane & 15;
  int mrow = m0 + wave * 16 + l15;

  U4B af[4];
#pragma unroll
  for (int dk = 0; dk < 4; ++dk) {
    const float* Af = A + (size_t)mrow * 128 + dk * 32 + quad * 8;
    float4 a = *(const float4*)Af;
    float4 b = *(const float4*)(Af + 4);
    af[dk].u = make_uint4(pkbf(a.x, a.y), pkbf(a.z, a.w),
                          pkbf(b.x, b.y), pkbf(b.z, b.w));
  }

  int gbase = m0 + wave * 16 + quad * 4;
  int bb = gbase >> 10, n0 = gbase & 1023;

#pragma unroll
  for (int s = 0; s < 2; ++s) {
    int mode = pg * 2 + s;
    const u16* WtG = WtAll + mode * 16384;
    if (s) __syncthreads();  // all Wl reads of s=0 done before restage
#pragma unroll
    for (int r = 0; r < 8; ++r) {
      int i = r * 256 + tid;
      int e = i >> 4, j = i & 15;
      *(uint4*)&Wl[e * 136 + j * 8] = *(const uint4*)(WtG + e * 128 + j * 8);
    }
    __syncthreads();

    f32x4 c[8];
#pragma unroll
    for (int nt = 0; nt < 8; ++nt)
#pragma unroll
      for (int r = 0; r < 4; ++r) c[nt][r] = 0.f;
#pragma unroll
    for (int dk = 0; dk < 4; ++dk)
#pragma unroll
      for (int nt = 0; nt < 8; ++nt) {
        U4B bg;
        bg.u = *(const uint4*)&Wl[(nt * 16 + l15) * 136 + dk * 32 + quad * 8];
        c[nt] = __builtin_amdgcn_mfma_f32_16x16x32_bf16(af[dk].b, bg.b, c[nt], 0, 0, 0);
      }

    if (mode == 0) {
#pragma unroll
      for (int nt = 0; nt < 8; ++nt)
#pragma unroll
        for (int r = 0; r < 4; ++r) {
          int n = n0 + r;
          if (n < NST) continue;  // prep owns station rows of Qm
          Qm[(((size_t)nt * 32 + bb) * 1024 + n) * 16 + l15] = bf1(c[nt][r] * SCL);
        }
    } else if (mode == 1) {
#pragma unroll
      for (int nt = 0; nt < 8; ++nt)
#pragma unroll
        for (int r = 0; r < 4; ++r)
          Qts[(((size_t)nt * 32 + bb) * 1024 + n0 + r) * 16 + l15] =
              bf1(c[nt][r] * SCL);
    } else if (mode == 2) {
#pragma unroll
      for (int nt = 0; nt < 8; ++nt)
#pragma unroll
        for (int r = 0; r < 4; ++r)
          Kc[(((size_t)nt * 32 + bb) * 1024 + n0 + r) * 16 + l15] = bf1(c[nt][r]);
    } else {
#pragma unroll
      for (int nt = 0; nt < 8; ++nt) {
        uint2 w2 = make_uint2(pkbf(c[nt][0], c[nt][1]), pkbf(c[nt][2], c[nt][3]));
        *(uint2*)(Vc + (((size_t)nt * 32 + bb) * 16 + l15) * 1024 + n0) = w2;
      }
    }
  }
}

// =====================================================================
// outproj: out(64 x 128) f32 = heads_bf16(64x128) @ W_out^T
// =====================================================================
__global__ __launch_bounds__(256) void outproj(
    const u16* __restrict__ heads, const u16* __restrict__ WtAll,
    float* __restrict__ out) {
  __shared__ u16 Wl[128 * 136];
  const u16* WtG = WtAll + 4 * 16384;
  int tid = threadIdx.x;
#pragma unroll
  for (int r = 0; r < 8; ++r) {
    int i = r * 256 + tid;
    int e = i >> 4, j = i & 15;
    *(uint4*)&Wl[e * 136 + j * 8] = *(const uint4*)(WtG + e * 128 + j * 8);
  }
  __syncthreads();
  int wave = tid >> 6, lane = tid & 63;
  int quad = lane >> 4, l15 = lane & 15;
  int m0 = blockIdx.x * 64;
  int mrow = m0 + wave * 16 + l15;

  f32x4 c[8];
#pragma unroll
  for (int nt = 0; nt < 8; ++nt)
#pragma unroll
    for (int r = 0; r < 4; ++r) c[nt][r] = 0.f;
#pragma unroll
  for (int dk = 0; dk < 4; ++dk) {
    U4B af;
    af.u = *(const uint4*)(heads + (size_t)mrow * 128 + dk * 32 + quad * 8);
#pragma unroll
    for (int nt = 0; nt < 8; ++nt) {
      U4B bg;
      bg.u = *(const uint4*)&Wl[(nt * 16 + l15) * 136 + dk * 32 + quad * 8];
      c[nt] = __builtin_amdgcn_mfma_f32_16x16x32_bf16(af.b, bg.b, c[nt], 0, 0, 0);
    }
  }
  int gbase = m0 + wave * 16 + quad * 4;
#pragma unroll
  for (int nt = 0; nt < 8; ++nt)
#pragma unroll
    for (int r = 0; r < 4; ++r)
      out[(size_t)(gbase + r) * 128 + nt * 16 + l15] = c[nt][r];
}

// =====================================================================
// attn_main v2 (occupancy restructure): QBLK=128 per block (was 256),
// grid 2048 = 8 qc x 256 hb; each of 4 waves owns 32 q rows -> single
// 32x32 S-fragment, o/la halved, Pt halved (LDS 32->23.4 KB).
// __launch_bounds__(256,8) pins VGPR<=64 -> 8 waves/SIMD allowed;
// resident target 6 blocks/CU (LDS-capped) = 24 waves/CU = 75%.
// Same-hb blocks are 256 apart -> same XCD (mod 8) -> shared L2 K/V.
// All LDS strides identical to the verified r2 kernel.
// =====================================================================
__global__ __launch_bounds__(256, 8) void attn_main(
    const u16* __restrict__ Qm, const u16* __restrict__ Qts,
    const u16* __restrict__ Kc, const u16* __restrict__ Vc,
    const u16* __restrict__ Ks, const u16* __restrict__ Vs,
    u16* __restrict__ heads) {
  int bx = blockIdx.x;
  int hb = bx & 255, qc = bx >> 8;   // qc 0..7
  int h = hb >> 5, b = hb & 31;
  int tid = threadIdx.x;
  int wave = tid >> 6, lane = tid & 63;
  int l5 = lane >> 5, l31 = lane & 31;
  int quad = lane >> 4, l15 = lane & 15;

  __shared__ u16 Kl[128 * 26];     // [key][26]: 52B rows, 13-bank step (gcd 1)
  __shared__ u16 Vl[16 * 140];     // [k][140]: 280B rows (gcd 2)
  __shared__ u16 Pt[4][32 * 36];   // per wave [q32][36]: 72B rows, 8B-aligned
  __shared__ u16 KsL[32 * 26];     // station keys
  __shared__ u16 VsL[16 * 44];     // station values transposed

  const u16* Qbase = Qm + ((size_t)(h * 32 + b)) * 16384;
  const u16* QtsB = Qts + ((size_t)(h * 32 + b)) * 16384;
  const u16* Kbase = Kc + ((size_t)(h * 32 + b)) * 16384;
  const u16* Vbase = Vc + ((size_t)(h * 32 + b)) * 16384;
  const u16* KsB = Ks + (size_t)(h * 32 + b) * 512;
  const u16* VsB = Vs + (size_t)(h * 32 + b) * 512;

  // stage station K/V once (visible after first loop barrier)
  if (tid < 64) {
    int key = tid >> 1, half = tid & 1;
    *(uint4*)&KsL[key * 26 + half * 8] = *(const uint4*)(KsB + key * 16 + half * 8);
  } else if (tid < 128) {
    int t = tid - 64;
    int d = t >> 2, kg = t & 3;
    *(uint4*)&VsL[d * 44 + kg * 8] = *(const uint4*)(VsB + d * 32 + kg * 8);
  }

  int qw0 = qc * 128 + wave * 32;
  U4B qf;
  qf.u = *(const uint4*)(Qbase + (size_t)(qw0 + l31) * 16 + l5 * 8);

  // T14 prefetch: tile 0 into regs
  int skey = tid >> 1, shalf = tid & 1;   // K stage mapping
  int sd = tid >> 4, skg = tid & 15;      // V stage mapping
  uint4 kpre = *(const uint4*)(Kbase + (size_t)skey * 16 + shalf * 8);
  uint4 vpre = *(const uint4*)(Vbase + (size_t)sd * 1024 + skg * 8);

  f32x16 zero16;
#pragma unroll
  for (int i = 0; i < 16; ++i) zero16[i] = 0.f;
  U4B ones;
  ones.u = make_uint4(0x3F803F80u, 0x3F803F80u, 0x3F803F80u, 0x3F803F80u);

  f32x4 o[2], la[2];
#pragma unroll
  for (int mt = 0; mt < 2; ++mt)
#pragma unroll
    for (int r = 0; r < 4; ++r) { o[mt][r] = 0.f; la[mt][r] = 0.f; }

#pragma unroll 1
  for (int kb = 0; kb < 8; ++kb) {
    __syncthreads();  // previous tile's compute done reading Kl/Vl
    *(uint4*)&Kl[skey * 26 + shalf * 8] = kpre;
    *(uint4*)&Vl[sd * 140 + skg * 8] = vpre;
    if (kb < 7) {  // issue next tile; completes under this tile's compute
      int j0n = (kb + 1) * 128;
      kpre = *(const uint4*)(Kbase + (size_t)(j0n + skey) * 16 + shalf * 8);
      vpre = *(const uint4*)(Vbase + (size_t)sd * 1024 + j0n + skg * 8);
    }
    __syncthreads();
#pragma unroll 1
    for (int kt = 0; kt < 4; ++kt) {
      int key0 = kt * 32;
      U4B af;
      af.u = *(const uint4*)&Kl[(key0 + l31) * 26 + l5 * 8];
      f32x16 c0 =
          __builtin_amdgcn_mfma_f32_32x32x16_bf16(af.b, qf.b, zero16, 0, 0, 0);
      bool masked = (kb == 0) && (kt == 0);
#pragma unroll
      for (int g = 0; g < 4; ++g) {
        float p0 = __builtin_amdgcn_exp2f(c0[4 * g + 0]);
        float p1 = __builtin_amdgcn_exp2f(c0[4 * g + 1]);
        float p2 = __builtin_amdgcn_exp2f(c0[4 * g + 2]);
        float p3 = __builtin_amdgcn_exp2f(c0[4 * g + 3]);
        if (masked) {  // key index of value r is r + 8*g + 4*l5; zero keys<21
          int kb0 = 8 * g + 4 * l5;
          p0 = (kb0 + 0 < NST) ? 0.f : p0;
          p1 = (kb0 + 1 < NST) ? 0.f : p1;
          p2 = (kb0 + 2 < NST) ? 0.f : p2;
          p3 = (kb0 + 3 < NST) ? 0.f : p3;
        }
        uint2 w2 = make_uint2(pkperm(p0, p1), pkperm(p2, p3));
        *(uint2*)&Pt[wave][l31 * 36 + 4 * l5 + 8 * g] = w2;
      }
      U4B vf;
      vf.u = *(const uint4*)&Vl[l15 * 140 + key0 + quad * 8];
#pragma unroll
      for (int mt = 0; mt < 2; ++mt) {
        U4B pf;
        pf.u = *(const uint4*)&Pt[wave][(mt * 16 + l15) * 36 + quad * 8];
        o[mt] = __builtin_amdgcn_mfma_f32_16x16x32_bf16(pf.b, vf.b, o[mt], 0, 0, 0);
        la[mt] =
            __builtin_amdgcn_mfma_f32_16x16x32_bf16(pf.b, ones.b, la[mt], 0, 0, 0);
      }
    }
  }

  // ---- fused station pass: Q = Q_ts, keys = K_s/V_s (keys>=21 masked) ----
  f32x4 o2[2], la2[2];
#pragma unroll
  for (int mt = 0; mt < 2; ++mt)
#pragma unroll
    for (int r = 0; r < 4; ++r) { o2[mt][r] = 0.f; la2[mt][r] = 0.f; }
  qf.u = *(const uint4*)(QtsB + (size_t)(qw0 + l31) * 16 + l5 * 8);
  {
    U4B af;
    af.u = *(const uint4*)&KsL[l31 * 26 + l5 * 8];
    f32x16 c0 =
        __builtin_amdgcn_mfma_f32_32x32x16_bf16(af.b, qf.b, zero16, 0, 0, 0);
#pragma unroll
    for (int g = 0; g < 4; ++g) {
      float p0 = __builtin_amdgcn_exp2f(c0[4 * g + 0]);
      float p1 = __builtin_amdgcn_exp2f(c0[4 * g + 1]);
      float p2 = __builtin_amdgcn_exp2f(c0[4 * g + 2]);
      float p3 = __builtin_amdgcn_exp2f(c0[4 * g + 3]);
      int kb0 = 8 * g + 4 * l5;  // zero keys >= 21 (pad rows)
      p0 = (kb0 + 0 >= NST) ? 0.f : p0;
      p1 = (kb0 + 1 >= NST) ? 0.f : p1;
      p2 = (kb0 + 2 >= NST) ? 0.f : p2;
      p3 = (kb0 + 3 >= NST) ? 0.f : p3;
      uint2 w2 = make_uint2(pkperm(p0, p1), pkperm(p2, p3));
      *(uint2*)&Pt[wave][l31 * 36 + 4 * l5 + 8 * g] = w2;
    }
    U4B vf;
    vf.u = *(const uint4*)&VsL[l15 * 44 + quad * 8];
#pragma unroll
    for (int mt = 0; mt < 2; ++mt) {
      U4B pf;
      pf.u = *(const uint4*)&Pt[wave][(mt * 16 + l15) * 36 + quad * 8];
      o2[mt] = __builtin_amdgcn_mfma_f32_16x16x32_bf16(pf.b, vf.b, o2[mt], 0, 0, 0);
      la2[mt] =
          __builtin_amdgcn_mfma_f32_16x16x32_bf16(pf.b, ones.b, la2[mt], 0, 0, 0);
    }
  }

  // ---- epilogue: heads bf16 ----
#pragma unroll
  for (int mt = 0; mt < 2; ++mt)
#pragma unroll
    for (int r = 0; r < 4; ++r) {
      int n = qw0 + mt * 16 + quad * 4 + r;
      float val = o[mt][r] * __builtin_amdgcn_rcpf(la[mt][r]);
      if (n >= NST) val += o2[mt][r] * __builtin_amdgcn_rcpf(la2[mt][r]);
      heads[((size_t)b * 1024 + n) * 128 + h * 16 + l15] = bf1(val);
    }
}

// =====================================================================
extern "C" void kernel_launch(void* const* d_in, const int* in_sizes, int n_in,
                              void* d_out, int out_size, void* d_ws,
                              size_t ws_size, hipStream_t stream) {
  (void)in_sizes; (void)n_in; (void)out_size; (void)ws_size;
  const float* q     = (const float*)d_in[0];
  const float* hx    = (const float*)d_in[1];
  const float* W_qts = (const float*)d_in[2];  // W_query_custom   -> Q_ts
  const float* W_qtt = (const float*)d_in[3];  // W_query_custom_1 -> Q_tt
  const float* W_kc  = (const float*)d_in[4];
  const float* W_vc  = (const float*)d_in[5];
  const float* W_qst = (const float*)d_in[6];  // W_query_charge_1 -> Q_st
  const float* W_ks  = (const float*)d_in[7];
  const float* W_vs  = (const float*)d_in[8];
  const float* W_out = (const float*)d_in[9];

  char* ws = (char*)d_ws;
  u16* heads = (u16*)(ws + 0);          // bf16 heads
  u16* Qm    = (u16*)(ws + 16777216);   // [h][b][1024][16]
  u16* Qts   = (u16*)(ws + 25165824);
  u16* Kc    = (u16*)(ws + 33554432);   // [h][b][1024][16]
  u16* Vc    = (u16*)(ws + 41943040);   // [h][b][16][1024] (transposed)
  u16* Ks    = (u16*)(ws + 50331648);   // [h][b][32][16]
  u16* Vs    = (u16*)(ws + 50593792);   // [h][b][16][32]
  u16* WtAll = (u16*)(ws + 50855936);   // 5 x 128x128 bf16

  hipLaunchKernelGGL(prep, dim3(552), dim3(256), 0, stream,
                     q, hx, W_qtt, W_qts, W_kc, W_vc, W_out, W_qst, W_ks, W_vs,
                     WtAll, Qm, Ks, Vs);
  hipLaunchKernelGGL(proj_pair, dim3(1024), dim3(256), 0, stream,
                     q, hx, WtAll, Qm, Qts, Kc, Vc);
  hipLaunchKernelGGL(attn_main, dim3(2048), dim3(256), 0, stream,
                     Qm, Qts, Kc, Vc, Ks, Vs, heads);
  hipLaunchKernelGGL(outproj, dim3(512), dim3(256), 0, stream,
                     heads, WtAll, (float*)d_out);
}

// Round 5
// 160.208 us; speedup vs baseline: 1.0824x; 1.0580x over previous
//
#include <hip/hip_runtime.h>

typedef __bf16 bf16x8 __attribute__((ext_vector_type(8)));
typedef float f32x4 __attribute__((ext_vector_type(4)));
typedef float f32x16 __attribute__((ext_vector_type(16)));
typedef unsigned int uint32;
typedef unsigned short u16;

#define NST 21
#define TOK 1003
#define SCL 0.3606737602222409f  // 0.25*log2(e); softmax = exp2(s), shift-free

union U4B { uint4 u; bf16x8 b; };

__device__ __forceinline__ uint32 pkbf(float a, float b) {  // RTNE pack
  uint32 ua = __float_as_uint(a), ub = __float_as_uint(b);
  ua += 0x7fffu + ((ua >> 16) & 1u);
  ub += 0x7fffu + ((ub >> 16) & 1u);
  return (ua >> 16) | (ub & 0xffff0000u);
}
__device__ __forceinline__ u16 bf1(float a) {
  uint32 u = __float_as_uint(a);
  u += 0x7fffu + ((u >> 16) & 1u);
  return (u16)(u >> 16);
}
// 1-instr truncating pack: lo16 = lo.hi16, hi16 = hi.hi16 (CK idiom)
__device__ __forceinline__ uint32 pkperm(float lo, float hi) {
  return __builtin_amdgcn_perm(__float_as_uint(hi), __float_as_uint(lo), 0x07060302u);
}
// half-wave swap: a' = {a.lanes0-31 | b.lanes0-31}, b' = {a.lanes32-63 | b.lanes32-63}
__device__ __forceinline__ void plswap(uint32& a, uint32& b) {
#if __has_builtin(__builtin_amdgcn_permlane32_swap)
  typedef unsigned int uu2 __attribute__((ext_vector_type(2)));
  uu2 r = __builtin_amdgcn_permlane32_swap(a, b, false, false);
  a = r.x; b = r.y;
#else
  asm volatile("v_permlane32_swap_b32 %0, %1" : "+v"(a), "+v"(b));
#endif
}

// =====================================================================
// prep: (a) 5 weight transposes -> bf16 WtAll (40 blocks, 8 per matrix),
// (b) station projections Q_st->Qm rows<21, K_s/V_s (+zero pad rows
// 21..32). grid 552 = 40 + 512
// =====================================================================
__global__ __launch_bounds__(256) void prep(
    const float* __restrict__ q, const float* __restrict__ hx,
    const float* __restrict__ W0, const float* __restrict__ W1,
    const float* __restrict__ W2, const float* __restrict__ W3,
    const float* __restrict__ W4, const float* __restrict__ Wqst,
    const float* __restrict__ Wks, const float* __restrict__ Wvs,
    u16* __restrict__ WtAll, u16* __restrict__ Qm,
    u16* __restrict__ Ks, u16* __restrict__ Vs) {
  int bid = blockIdx.x, tid = threadIdx.x;
  __shared__ float xq2[2][128], xh2[2][128];
  if (bid < 40) {
    int w = bid >> 3, seg = bid & 7;
    const float* W = (w == 0) ? W0 : (w == 1) ? W1 : (w == 2) ? W2
                     : (w == 3) ? W3 : W4;
    u16* dst = WtAll + w * 16384;
#pragma unroll
    for (int it = 0; it < 8; ++it) {
      int i = seg * 2048 + it * 256 + tid;  // 0..16383
      int inner = i & 127, outer = i >> 7;
      float v;
      if (w < 4) {
        int h = outer >> 4, k = outer & 15;
        v = W[h * 2048 + inner * 16 + k];
      } else {
        v = W[inner * 128 + outer];
      }
      dst[outer * 128 + inner] = bf1(v);
    }
  } else {
    int t2 = bid - 40;              // 0..511
    int sub = tid >> 7, col = tid & 127;
    int hh = col >> 4, k = col & 15;
    int bs2 = t2 * 2 + sub;         // 0..1023
    int b2 = bs2 >> 5, s = bs2 & 31;
    if (s < NST) {
      xq2[sub][col] = q[(size_t)(b2 * 1024 + s) * 128 + col];
      xh2[sub][col] = hx[(size_t)(b2 * 1024 + s) * 128 + col];
    }
    __syncthreads();
    if (s < NST) {
      const float* Wq = Wqst + hh * 2048 + k;
      const float* Wk = Wks + hh * 2048 + k;
      const float* Wv = Wvs + hh * 2048 + k;
      float dq = 0.f, dk_ = 0.f, dv = 0.f;
#pragma unroll 8
      for (int d = 0; d < 128; ++d) {
        float xq = xq2[sub][d], xh = xh2[sub][d];
        dq = fmaf(xq, Wq[d * 16], dq);
        dk_ = fmaf(xh, Wk[d * 16], dk_);
        dv = fmaf(xh, Wv[d * 16], dv);
      }
      Qm[(((size_t)hh * 32 + b2) * 1024 + s) * 16 + k] = bf1(dq * SCL);
      Ks[(((size_t)hh * 32 + b2) * 32 + s) * 16 + k] = bf1(dk_);
      Vs[(((size_t)hh * 32 + b2) * 16 + k) * 32 + s] = bf1(dv);
    } else {
      Ks[(((size_t)hh * 32 + b2) * 32 + s) * 16 + k] = 0;
      Vs[(((size_t)hh * 32 + b2) * 16 + k) * 32 + s] = 0;
    }
  }
}

// =====================================================================
// proj_pair: one block computes BOTH projections sharing an A tile.
// pg=0: q -> Qm (mode0: scaled, skip n<21) and Qts (mode1: scaled)
// pg=1: hx -> Kc (mode2) and Vc (mode3: transposed [h][b][k16][n1024])
// grid 1024 = 2 x 512
// =====================================================================
__global__ __launch_bounds__(256) void proj_pair(
    const float* __restrict__ q, const float* __restrict__ hx,
    const u16* __restrict__ WtAll, u16* __restrict__ Qm,
    u16* __restrict__ Qts, u16* __restrict__ Kc, u16* __restrict__ Vc) {
  __shared__ u16 Wl[128 * 136];
  int pg = blockIdx.x >> 9, mb = blockIdx.x & 511;
  int m0 = mb * 64;
  const float* A = pg ? hx : q;
  int tid = threadIdx.x;
  int wave = tid >> 6, lane = tid & 63;
  int quad = lane >> 4, l15 = lane & 15;
  int mrow = m0 + wave * 16 + l15;

  U4B af[4];
#pragma unroll
  for (int dk = 0; dk < 4; ++dk) {
    const float* Af = A + (size_t)mrow * 128 + dk * 32 + quad * 8;
    float4 a = *(const float4*)Af;
    float4 b = *(const float4*)(Af + 4);
    af[dk].u = make_uint4(pkbf(a.x, a.y), pkbf(a.z, a.w),
                          pkbf(b.x, b.y), pkbf(b.z, b.w));
  }

  int gbase = m0 + wave * 16 + quad * 4;
  int bb = gbase >> 10, n0 = gbase & 1023;

#pragma unroll
  for (int s = 0; s < 2; ++s) {
    int mode = pg * 2 + s;
    const u16* WtG = WtAll + mode * 16384;
    if (s) __syncthreads();  // all Wl reads of s=0 done before restage
#pragma unroll
    for (int r = 0; r < 8; ++r) {
      int i = r * 256 + tid;
      int e = i >> 4, j = i & 15;
      *(uint4*)&Wl[e * 136 + j * 8] = *(const uint4*)(WtG + e * 128 + j * 8);
    }
    __syncthreads();

    f32x4 c[8];
#pragma unroll
    for (int nt = 0; nt < 8; ++nt)
#pragma unroll
      for (int r = 0; r < 4; ++r) c[nt][r] = 0.f;
#pragma unroll
    for (int dk = 0; dk < 4; ++dk)
#pragma unroll
      for (int nt = 0; nt < 8; ++nt) {
        U4B bg;
        bg.u = *(const uint4*)&Wl[(nt * 16 + l15) * 136 + dk * 32 + quad * 8];
        c[nt] = __builtin_amdgcn_mfma_f32_16x16x32_bf16(af[dk].b, bg.b, c[nt], 0, 0, 0);
      }

    if (mode == 0) {
#pragma unroll
      for (int nt = 0; nt < 8; ++nt)
#pragma unroll
        for (int r = 0; r < 4; ++r) {
          int n = n0 + r;
          if (n < NST) continue;  // prep owns station rows of Qm
          Qm[(((size_t)nt * 32 + bb) * 1024 + n) * 16 + l15] = bf1(c[nt][r] * SCL);
        }
    } else if (mode == 1) {
#pragma unroll
      for (int nt = 0; nt < 8; ++nt)
#pragma unroll
        for (int r = 0; r < 4; ++r)
          Qts[(((size_t)nt * 32 + bb) * 1024 + n0 + r) * 16 + l15] =
              bf1(c[nt][r] * SCL);
    } else if (mode == 2) {
#pragma unroll
      for (int nt = 0; nt < 8; ++nt)
#pragma unroll
        for (int r = 0; r < 4; ++r)
          Kc[(((size_t)nt * 32 + bb) * 1024 + n0 + r) * 16 + l15] = bf1(c[nt][r]);
    } else {
#pragma unroll
      for (int nt = 0; nt < 8; ++nt) {
        uint2 w2 = make_uint2(pkbf(c[nt][0], c[nt][1]), pkbf(c[nt][2], c[nt][3]));
        *(uint2*)(Vc + (((size_t)nt * 32 + bb) * 16 + l15) * 1024 + n0) = w2;
      }
    }
  }
}

// =====================================================================
// outproj: out(64 x 128) f32 = heads_bf16(64x128) @ W_out^T
// =====================================================================
__global__ __launch_bounds__(256) void outproj(
    const u16* __restrict__ heads, const u16* __restrict__ WtAll,
    float* __restrict__ out) {
  __shared__ u16 Wl[128 * 136];
  const u16* WtG = WtAll + 4 * 16384;
  int tid = threadIdx.x;
#pragma unroll
  for (int r = 0; r < 8; ++r) {
    int i = r * 256 + tid;
    int e = i >> 4, j = i & 15;
    *(uint4*)&Wl[e * 136 + j * 8] = *(const uint4*)(WtG + e * 128 + j * 8);
  }
  __syncthreads();
  int wave = tid >> 6, lane = tid & 63;
  int quad = lane >> 4, l15 = lane & 15;
  int m0 = blockIdx.x * 64;
  int mrow = m0 + wave * 16 + l15;

  f32x4 c[8];
#pragma unroll
  for (int nt = 0; nt < 8; ++nt)
#pragma unroll
    for (int r = 0; r < 4; ++r) c[nt][r] = 0.f;
#pragma unroll
  for (int dk = 0; dk < 4; ++dk) {
    U4B af;
    af.u = *(const uint4*)(heads + (size_t)mrow * 128 + dk * 32 + quad * 8);
#pragma unroll
    for (int nt = 0; nt < 8; ++nt) {
      U4B bg;
      bg.u = *(const uint4*)&Wl[(nt * 16 + l15) * 136 + dk * 32 + quad * 8];
      c[nt] = __builtin_amdgcn_mfma_f32_16x16x32_bf16(af.b, bg.b, c[nt], 0, 0, 0);
    }
  }
  int gbase = m0 + wave * 16 + quad * 4;
#pragma unroll
  for (int nt = 0; nt < 8; ++nt)
#pragma unroll
    for (int r = 0; r < 4; ++r)
      out[(size_t)(gbase + r) * 128 + nt * 16 + l15] = c[nt][r];
}

// =====================================================================
// attn_main v3 (issue-count reduction): no P LDS round-trip, no la-MFMA.
// Per kt: S^T = mfma_32x32x16(K, Q); exp2+pkperm pack P^T in-register;
// 4x v_permlane32_swap build PV B-fragments (B[k][q], lane n=l31,
// k=(l>>5)*8+j) directly from the packed words; O^T = mfma_32x32x16
// (A = V^T from Vl rows 0-15, rows 16-31 = 1.0 -> denominator rows for
// free). One f32x16 accumulator: rows 0-15 = O^T, rows 16-31 = la.
// Station pass runs FIRST, reduced to contrib[8] regs. LDS 19.6 KB ->
// 8 blocks/CU; grid 2048 = 8 qc x 256 hb.
// =====================================================================
__global__ __launch_bounds__(256, 8) void attn_main(
    const u16* __restrict__ Qm, const u16* __restrict__ Qts,
    const u16* __restrict__ Kc, const u16* __restrict__ Vc,
    const u16* __restrict__ Ks, const u16* __restrict__ Vs,
    u16* __restrict__ heads) {
  int bx = blockIdx.x;
  int hb = bx & 255, qc = bx >> 8;   // qc 0..7
  int h = hb >> 5, b = hb & 31;
  int tid = threadIdx.x;
  int wave = tid >> 6, lane = tid & 63;
  int l5 = lane >> 5, l31 = lane & 31;

  __shared__ u16 Kl[128 * 26];   // [key][26]: 52B rows, 13-bank step
  __shared__ u16 Vl[32 * 140];   // rows 0-15: V^T tile; rows 16-31: 1.0
  __shared__ u16 KsL[32 * 26];   // station keys
  __shared__ u16 VsL[32 * 44];   // rows 0-15: V_s^T; rows 16-31: 1.0

  const u16* Qbase = Qm + ((size_t)(h * 32 + b)) * 16384;
  const u16* QtsB = Qts + ((size_t)(h * 32 + b)) * 16384;
  const u16* Kbase = Kc + ((size_t)(h * 32 + b)) * 16384;
  const u16* Vbase = Vc + ((size_t)(h * 32 + b)) * 16384;
  const u16* KsB = Ks + (size_t)(h * 32 + b) * 512;
  const u16* VsB = Vs + (size_t)(h * 32 + b) * 512;

  uint4 ones4 = make_uint4(0x3F803F80u, 0x3F803F80u, 0x3F803F80u, 0x3F803F80u);

  // ---- stage station K/V + ones rows (visible after first barrier) ----
  if (tid < 64) {
    int key = tid >> 1, half = tid & 1;
    *(uint4*)&KsL[key * 26 + half * 8] = *(const uint4*)(KsB + key * 16 + half * 8);
  } else if (tid < 128) {
    int t = tid - 64;
    int d = t >> 2, kg = t & 3;
    *(uint4*)&VsL[d * 44 + kg * 8] = *(const uint4*)(VsB + d * 32 + kg * 8);
  } else if (tid < 192) {
    int t = tid - 128;  // VsL ones rows 16-31, cols 0-31: 64 x b128
    *(uint4*)&VsL[(16 + (t >> 2)) * 44 + (t & 3) * 8] = ones4;
  }
  // Vl ones rows 16-31, cols 0-127: 256 x b128 (one per thread); persist
  // across all kb stages (staging only writes rows 0-15).
  *(uint4*)&Vl[(16 + (tid >> 4)) * 140 + (tid & 15) * 8] = ones4;

  // T14 prefetch: main-loop tile 0 (latency hides under station pass)
  int skey = tid >> 1, shalf = tid & 1;   // K stage mapping
  int sd = tid >> 4, skg = tid & 15;      // V stage mapping (rows 0-15)
  uint4 kpre = *(const uint4*)(Kbase + (size_t)skey * 16 + shalf * 8);
  uint4 vpre = *(const uint4*)(Vbase + (size_t)sd * 1024 + skg * 8);

  int qw0 = qc * 128 + wave * 32;
  int qrow = qw0 + l31;

  f32x16 zero16;
#pragma unroll
  for (int i = 0; i < 16; ++i) zero16[i] = 0.f;

  // ---- station pass first: contrib[8] = (P_s V_s / la_s) rows ----
  U4B qf;
  qf.u = *(const uint4*)(QtsB + (size_t)qrow * 16 + l5 * 8);
  __syncthreads();  // KsL/VsL (+ones) visible
  float contrib[8];
  {
    U4B af;
    af.u = *(const uint4*)&KsL[l31 * 26 + l5 * 8];
    f32x16 c0 =
        __builtin_amdgcn_mfma_f32_32x32x16_bf16(af.b, qf.b, zero16, 0, 0, 0);
    uint32 w[8];
#pragma unroll
    for (int g = 0; g < 4; ++g) {
      float p0 = __builtin_amdgcn_exp2f(c0[4 * g + 0]);
      float p1 = __builtin_amdgcn_exp2f(c0[4 * g + 1]);
      float p2 = __builtin_amdgcn_exp2f(c0[4 * g + 2]);
      float p3 = __builtin_amdgcn_exp2f(c0[4 * g + 3]);
      int kb0 = 8 * g + 4 * l5;  // zero keys >= 21 (pad rows)
      p0 = (kb0 + 0 >= NST) ? 0.f : p0;
      p1 = (kb0 + 1 >= NST) ? 0.f : p1;
      p2 = (kb0 + 2 >= NST) ? 0.f : p2;
      p3 = (kb0 + 3 >= NST) ? 0.f : p3;
      w[2 * g] = pkperm(p0, p1);
      w[2 * g + 1] = pkperm(p2, p3);
    }
    plswap(w[0], w[2]); plswap(w[1], w[3]);
    plswap(w[4], w[6]); plswap(w[5], w[7]);
    U4B b1, b2, a1, a2;
    b1.u = make_uint4(w[0], w[1], w[2], w[3]);
    b2.u = make_uint4(w[4], w[5], w[6], w[7]);
    a1.u = *(const uint4*)&VsL[l31 * 44 + l5 * 8];
    a2.u = *(const uint4*)&VsL[l31 * 44 + 16 + l5 * 8];
    f32x16 acc2 =
        __builtin_amdgcn_mfma_f32_32x32x16_bf16(a1.b, b1.b, zero16, 0, 0, 0);
    acc2 = __builtin_amdgcn_mfma_f32_32x32x16_bf16(a2.b, b2.b, acc2, 0, 0, 0);
    float rla2 = __builtin_amdgcn_rcpf(acc2[8]);  // ones row m=16+4*l5
#pragma unroll
    for (int r = 0; r < 8; ++r) contrib[r] = acc2[r] * rla2;
  }

  // ---- main pass over Kc/Vc ----
  qf.u = *(const uint4*)(Qbase + (size_t)qrow * 16 + l5 * 8);
  f32x16 acc;
#pragma unroll
  for (int i = 0; i < 16; ++i) acc[i] = 0.f;

#pragma unroll 1
  for (int kb = 0; kb < 8; ++kb) {
    __syncthreads();  // previous tile's compute done reading Kl/Vl
    *(uint4*)&Kl[skey * 26 + shalf * 8] = kpre;
    *(uint4*)&Vl[sd * 140 + skg * 8] = vpre;
    if (kb < 7) {  // issue next tile; completes under this tile's compute
      int j0n = (kb + 1) * 128;
      kpre = *(const uint4*)(Kbase + (size_t)(j0n + skey) * 16 + shalf * 8);
      vpre = *(const uint4*)(Vbase + (size_t)sd * 1024 + j0n + skg * 8);
    }
    __syncthreads();
#pragma unroll 1
    for (int kt = 0; kt < 4; ++kt) {
      int key0 = kt * 32;
      U4B af;
      af.u = *(const uint4*)&Kl[(key0 + l31) * 26 + l5 * 8];
      f32x16 c0 =
          __builtin_amdgcn_mfma_f32_32x32x16_bf16(af.b, qf.b, zero16, 0, 0, 0);
      bool masked = (kb == 0) && (kt == 0);
      uint32 w[8];
#pragma unroll
      for (int g = 0; g < 4; ++g) {
        float p0 = __builtin_amdgcn_exp2f(c0[4 * g + 0]);
        float p1 = __builtin_amdgcn_exp2f(c0[4 * g + 1]);
        float p2 = __builtin_amdgcn_exp2f(c0[4 * g + 2]);
        float p3 = __builtin_amdgcn_exp2f(c0[4 * g + 3]);
        if (masked) {  // key index of value r is r + 8*g + 4*l5; zero keys<21
          int kb0 = 8 * g + 4 * l5;
          p0 = (kb0 + 0 < NST) ? 0.f : p0;
          p1 = (kb0 + 1 < NST) ? 0.f : p1;
          p2 = (kb0 + 2 < NST) ? 0.f : p2;
          p3 = (kb0 + 3 < NST) ? 0.f : p3;
        }
        w[2 * g] = pkperm(p0, p1);
        w[2 * g + 1] = pkperm(p2, p3);
      }
      plswap(w[0], w[2]); plswap(w[1], w[3]);
      plswap(w[4], w[6]); plswap(w[5], w[7]);
      U4B b1, b2, a1, a2;
      b1.u = make_uint4(w[0], w[1], w[2], w[3]);
      b2.u = make_uint4(w[4], w[5], w[6], w[7]);
      a1.u = *(const uint4*)&Vl[l31 * 140 + key0 + l5 * 8];
      a2.u = *(const uint4*)&Vl[l31 * 140 + key0 + 16 + l5 * 8];
      acc = __builtin_amdgcn_mfma_f32_32x32x16_bf16(a1.b, b1.b, acc, 0, 0, 0);
      acc = __builtin_amdgcn_mfma_f32_32x32x16_bf16(a2.b, b2.b, acc, 0, 0, 0);
    }
  }

  // ---- epilogue: heads bf16 (lane l31 = q, l5 picks d-halves) ----
  // acc regs 0-3: d = 4*l5 + r; regs 4-7: d = 8 + 4*l5 + (r-4);
  // regs 8-15: la rows (all equal) -> use acc[8].
  {
    float rla = __builtin_amdgcn_rcpf(acc[8]);
    bool tok = (qrow >= NST);
    float v0 = acc[0] * rla + (tok ? contrib[0] : 0.f);
    float v1 = acc[1] * rla + (tok ? contrib[1] : 0.f);
    float v2 = acc[2] * rla + (tok ? contrib[2] : 0.f);
    float v3 = acc[3] * rla + (tok ? contrib[3] : 0.f);
    float v4 = acc[4] * rla + (tok ? contrib[4] : 0.f);
    float v5 = acc[5] * rla + (tok ? contrib[5] : 0.f);
    float v6 = acc[6] * rla + (tok ? contrib[6] : 0.f);
    float v7 = acc[7] * rla + (tok ? contrib[7] : 0.f);
    u16* hrow = heads + ((size_t)b * 1024 + qrow) * 128 + h * 16;
    *(uint2*)(hrow + 4 * l5) = make_uint2(pkbf(v0, v1), pkbf(v2, v3));
    *(uint2*)(hrow + 8 + 4 * l5) = make_uint2(pkbf(v4, v5), pkbf(v6, v7));
  }
}

// =====================================================================
extern "C" void kernel_launch(void* const* d_in, const int* in_sizes, int n_in,
                              void* d_out, int out_size, void* d_ws,
                              size_t ws_size, hipStream_t stream) {
  (void)in_sizes; (void)n_in; (void)out_size; (void)ws_size;
  const float* q     = (const float*)d_in[0];
  const float* hx    = (const float*)d_in[1];
  const float* W_qts = (const float*)d_in[2];  // W_query_custom   -> Q_ts
  const float* W_qtt = (const float*)d_in[3];  // W_query_custom_1 -> Q_tt
  const float* W_kc  = (const float*)d_in[4];
  const float* W_vc  = (const float*)d_in[5];
  const float* W_qst = (const float*)d_in[6];  // W_query_charge_1 -> Q_st
  const float* W_ks  = (const float*)d_in[7];
  const float* W_vs  = (const float*)d_in[8];
  const float* W_out = (const float*)d_in[9];

  char* ws = (char*)d_ws;
  u16* heads = (u16*)(ws + 0);          // bf16 heads
  u16* Qm    = (u16*)(ws + 16777216);   // [h][b][1024][16]
  u16* Qts   = (u16*)(ws + 25165824);
  u16* Kc    = (u16*)(ws + 33554432);   // [h][b][1024][16]
  u16* Vc    = (u16*)(ws + 41943040);   // [h][b][16][1024] (transposed)
  u16* Ks    = (u16*)(ws + 50331648);   // [h][b][32][16]
  u16* Vs    = (u16*)(ws + 50593792);   // [h][b][16][32]
  u16* WtAll = (u16*)(ws + 50855936);   // 5 x 128x128 bf16

  hipLaunchKernelGGL(prep, dim3(552), dim3(256), 0, stream,
                     q, hx, W_qtt, W_qts, W_kc, W_vc, W_out, W_qst, W_ks, W_vs,
                     WtAll, Qm, Ks, Vs);
  hipLaunchKernelGGL(proj_pair, dim3(1024), dim3(256), 0, stream,
                     q, hx, WtAll, Qm, Qts, Kc, Vc);
  hipLaunchKernelGGL(attn_main, dim3(2048), dim3(256), 0, stream,
                     Qm, Qts, Kc, Vc, Ks, Vs, heads);
  hipLaunchKernelGGL(outproj, dim3(512), dim3(256), 0, stream,
                     heads, WtAll, (float*)d_out);
}